// Round 8
// baseline (212.965 us; speedup 1.0000x reference)
//
#include <hip/hip_runtime.h>

// ---------------------------------------------------------------------------
// ANHPMultiHeadAttention: fused QKV projection + exp-scored causal attention
// B=8, S=1024, FEAT=HID=1024, H=8, DH=128.
//
// R8 changes vs R7:
//  - ATTRIBUTION: gemm split into 3 dispatches (mat arg; 512 blocks each =
//    2/CU exact, same occupancy math) and prep split into cast + transpose.
//    Every kernel now lands in rocprof top-5 -> full per-kernel counters.
//  - GEMM: reverted to R5's proven best (BK64 dbuf, 128B rows xor8, 0
//    conflicts, 69.5us) -- R7 showed BK32/16-waves is NOT better (LDS-BW
//    model: both cap at ~31% MfmaUtil; R5 avoids the dispatch tail).
//  - ATTN: R5's intensity (BQ=128, 32 q-rows/wave, kf+vf reused across 2
//    q-subtiles -> 576B LDS per MFMA, cap 27%) at BK=32 with R7's proven
//    conflict-free pair-interleaved Vs/Ps -> 40KB LDS. CU-paired qt
//    schedule (sums equal) + XCD pinning.
// ---------------------------------------------------------------------------

typedef __bf16 bf16x8 __attribute__((ext_vector_type(8)));
typedef float floatx4 __attribute__((ext_vector_type(4)));
typedef unsigned short u16;
typedef unsigned int u32;

#define RSCALE 0.08838834764831845f   // 1/sqrt(128)

__device__ __forceinline__ u16 f2b(float f) {       // fp32 -> bf16 bits, RNE
  union { float f; unsigned u; } v; v.f = f;
  return (u16)((v.u + 0x7FFFu + ((v.u >> 16) & 1u)) >> 16);
}

// async global->LDS, 16B per lane. LDS dst = wave-uniform base + lane*16.
__device__ __forceinline__ void gld_lds16(const void* g, void* l) {
  __builtin_amdgcn_global_load_lds(
      (const __attribute__((address_space(1))) unsigned*)g,
      (__attribute__((address_space(3))) unsigned*)l, 16, 0, 0);
}

#define MFMA16(a, b, c) __builtin_amdgcn_mfma_f32_16x16x32_bf16(a, b, c, 0, 0, 0)

// ---------------------------------------------------------------------------
// Kernel 1a: cast X fp32 -> bf16
// ---------------------------------------------------------------------------
__global__ __launch_bounds__(256) void cast_kernel(const float4* __restrict__ X,
                                                   u16* __restrict__ Xb) {
  unsigned i = blockIdx.x * 256u + threadIdx.x;
  float4 v = X[i];
  ushort4 o;
  o.x = f2b(v.x); o.y = f2b(v.y); o.z = f2b(v.z); o.w = f2b(v.w);
  *reinterpret_cast<ushort4*>(Xb + 4u * i) = o;
}

// ---------------------------------------------------------------------------
// Kernel 1b: transpose+cast W [K][N] fp32 -> Wt [N][K] bf16. grid (32,32,3).
// ---------------------------------------------------------------------------
__global__ __launch_bounds__(256) void transpose_kernel(
    const float* __restrict__ Wq, const float* __restrict__ Wk,
    const float* __restrict__ Wv, u16* __restrict__ Wtb) {
  const float* W = (blockIdx.z == 0) ? Wq : (blockIdx.z == 1) ? Wk : Wv;
  u16* Wt = Wtb + (size_t)blockIdx.z * (1024u * 1024u);
  __shared__ u16 tile[32][33];
  const int x = threadIdx.x, y = threadIdx.y;
  const int kt = blockIdx.x * 32, nt = blockIdx.y * 32;
#pragma unroll
  for (int i = 0; i < 4; ++i)
    tile[y + 8 * i][x] = f2b(W[(size_t)(kt + y + 8 * i) * 1024 + nt + x]);
  __syncthreads();
#pragma unroll
  for (int i = 0; i < 4; ++i)
    Wt[(size_t)(nt + y + 8 * i) * 1024 + kt + x] = tile[x][y + 8 * i];
}

// ---------------------------------------------------------------------------
// Kernel 2: QKV GEMM (R5-proven). 128x128 tile, BK=64, dbuf single-barrier,
// xor8 swizzle (0 conflicts). grid (64,8); `mat` selects matrix & output.
// ---------------------------------------------------------------------------
__global__ __launch_bounds__(256, 2) void gemm_qkv_kernel(
    const u16* __restrict__ Xb, const u16* __restrict__ Wtb,
    const float* __restrict__ bias, u16* __restrict__ outQK,
    u16* __restrict__ outVt, const int mat) {
  const u16* __restrict__ Wt = Wtb + (size_t)mat * (1024u * 1024u);

  const int m0 = blockIdx.x * 128;
  const int n0 = blockIdx.y * 128;

  __shared__ u16 As[2][128 * 64];   // [m][k] 16KB per buf, 128B rows
  __shared__ u16 Bs[2][128 * 64];   // [n][k]

  const int tid = threadIdx.x;
  const int wid = tid >> 6;
  const int lane = tid & 63;
  const int quad = lane >> 4;
  const int l16 = lane & 15;
  const int wm = (wid & 1) * 64;
  const int wn = (wid >> 1) * 64;

  const floatx4 z4 = {0.f, 0.f, 0.f, 0.f};
  floatx4 acc[4][4];
#pragma unroll
  for (int i = 0; i < 4; ++i)
#pragma unroll
    for (int j = 0; j < 4; ++j) acc[i][j] = z4;

  const int srow = wid * 32;
  const int lrow = lane >> 3;
  const int gblk = (lane & 7) ^ lrow;

  auto stage = [&](int b, int k0) {
#pragma unroll
    for (int c = 0; c < 4; ++c) {
      const int row = srow + c * 8 + lrow;
      gld_lds16(Xb + (size_t)(m0 + row) * 1024 + k0 + gblk * 8,
                As[b] + (srow + c * 8) * 64);
      gld_lds16(Wt + (size_t)(n0 + row) * 1024 + k0 + gblk * 8,
                Bs[b] + (srow + c * 8) * 64);
    }
  };

  stage(0, 0);

  for (int i = 0; i < 16; ++i) {
    __syncthreads();
    if (i < 15) stage((i + 1) & 1, (i + 1) * 64);

    const u16* __restrict__ Ab = As[i & 1];
    const u16* __restrict__ Bb = Bs[i & 1];
#pragma unroll
    for (int c = 0; c < 2; ++c) {
      const int phys = ((c * 4 + quad) ^ (l16 & 7)) * 8;
      bf16x8 af[4], bfr[4];
#pragma unroll
      for (int ii = 0; ii < 4; ++ii)
        af[ii] = *(const bf16x8*)(Ab + (wm + ii * 16 + l16) * 64 + phys);
#pragma unroll
      for (int j = 0; j < 4; ++j)
        bfr[j] = *(const bf16x8*)(Bb + (wn + j * 16 + l16) * 64 + phys);
#pragma unroll
      for (int ii = 0; ii < 4; ++ii)
#pragma unroll
        for (int j = 0; j < 4; ++j)
          acc[ii][j] = MFMA16(af[ii], bfr[j], acc[ii][j]);
    }
  }

  // epilogue. C/D layout: col = l16 (n), row = quad*4 + reg (m).
  const int b = m0 >> 10;
  const int h = n0 >> 7;
  const int sbase = (m0 & 1023) + wm;
  float bv4[4];
#pragma unroll
  for (int j = 0; j < 4; ++j) bv4[j] = bias[n0 + wn + j * 16 + l16];

  if (mat < 2) {
    u16* outp = outQK + (size_t)(b * 8 + h) * 1024 * 128;
#pragma unroll
    for (int i = 0; i < 4; ++i)
#pragma unroll
      for (int j = 0; j < 4; ++j) {
        const int d = wn + j * 16 + l16;
#pragma unroll
        for (int r = 0; r < 4; ++r) {
          const int s = sbase + i * 16 + quad * 4 + r;
          outp[(size_t)s * 128 + d] = f2b(acc[i][j][r] + bv4[j]);
        }
      }
  } else {
    // V^T: out[((b*8+h)*128 + d)*1024 + s]; 4 regs = 4 consecutive s.
    u16* outp = outVt + (size_t)(b * 8 + h) * 128 * 1024;
#pragma unroll
    for (int i = 0; i < 4; ++i)
#pragma unroll
      for (int j = 0; j < 4; ++j) {
        const int d = wn + j * 16 + l16;
        const int s = sbase + i * 16 + quad * 4;
        ushort4 pk;
        pk.x = f2b(acc[i][j][0] + bv4[j]);
        pk.y = f2b(acc[i][j][1] + bv4[j]);
        pk.z = f2b(acc[i][j][2] + bv4[j]);
        pk.w = f2b(acc[i][j][3] + bv4[j]);
        *(ushort4*)(outp + (size_t)d * 1024 + s) = pk;
      }
  }
}

// ---------------------------------------------------------------------------
// Kernel 3: attention. grid 512 (64 bh x 8 qtiles of 128), block 256
// (4 waves x 32 q-rows). BK=32, Ks+Vs double-buffered, one barrier/iter.
// kf reused across 2 q-subtiles (16 QK MFMA per 8KB) and vf reused across
// both pa (16 PV MFMA per 8KB) -> 576B LDS per MFMA (cap ~27%).
// Vs/Ps pair-interleaved 128B rows (R7-proven conflict-free). 40KB LDS.
// CU-paired qt schedule: (7,0),(4,3),(6,1),(5,2) -> equal work per CU.
// ---------------------------------------------------------------------------
__global__ __launch_bounds__(256, 2) void attn_kernel(const u16* __restrict__ Qh,
                                                      const u16* __restrict__ Kh,
                                                      const u16* __restrict__ Vt,
                                                      float* __restrict__ out) {
  const int id = blockIdx.x;
  const int bh = (id & 7) * 8 + ((id >> 3) & 7);   // XCD x owns 8 heads
  const int QTMAP[8] = {7, 4, 6, 5, 0, 3, 1, 2};   // pairs (g,g+4) sum equal
  const int qt = QTMAP[id >> 6];
  const int q0 = qt * 128;

  const int tid = threadIdx.x;
  const int wid = tid >> 6;
  const int lane = tid & 63;
  const int quad = lane >> 4;
  const int l16 = lane & 15;

  __shared__ u16 Ks[2][32 * 128];   // [key][d] 256B rows, xor16, 8KB each
  __shared__ u16 Vs[2][64 * 64];    // d-pair rows: 64 x 128B, 8KB each
  __shared__ u16 Ps[4][16 * 64];    // per-wave q-pair rows: 16 x 128B, 2KB

  const u16* __restrict__ Qbase = Qh + (size_t)bh * 1024 * 128;
  const u16* __restrict__ Kbase = Kh + (size_t)bh * 1024 * 128;
  const u16* __restrict__ Vbase = Vt + (size_t)bh * 128 * 1024;

  const int qw = q0 + wid * 32;     // this wave's 32 q-rows

  // Q B-frags (for S^T = MFMA(kf,qf)): lane l16 = q, k = quad*8+j.
  bf16x8 qf[2][4];
#pragma unroll
  for (int nt = 0; nt < 2; ++nt)
#pragma unroll
    for (int c = 0; c < 4; ++c)
      qf[nt][c] = *(const bf16x8*)(Qbase + (size_t)(qw + nt * 16 + l16) * 128 +
                                   c * 32 + quad * 8);

  const floatx4 z4 = {0.f, 0.f, 0.f, 0.f};
  floatx4 o[2][8];
#pragma unroll
  for (int nt = 0; nt < 2; ++nt)
#pragma unroll
    for (int dt = 0; dt < 8; ++dt) o[nt][dt] = z4;
  float lacc[2] = {0.f, 0.f};

  // staging lane pieces (R7-proven patterns)
  const int slr = lane >> 3;
  const int sp = lane & 7;
  const int ssub = sp >> 2;

  auto stage = [&](int b, int k0) {
    // K: 32 rows x 256B; wave stages 8 rows, 4 rows (1KB)/call, xor16.
#pragma unroll
    for (int c = 0; c < 2; ++c) {
      const int r0 = wid * 8 + c * 4;
      const int row = r0 + quad;
      gld_lds16(Kbase + (size_t)(k0 + row) * 128 + ((l16 ^ (row & 15)) * 8),
                Ks[b] + r0 * 128);
    }
    // V: 64 phys rows (d-pairs) x 128B; wave stages 16 rows, 8 rows/call.
#pragma unroll
    for (int c = 0; c < 2; ++c) {
      const int r = wid * 16 + c * 8 + slr;
      const int jj = (sp & 3) ^ (r & 3);
      gld_lds16(Vbase + (size_t)(2 * r + ssub) * 1024 + k0 + jj * 8,
                Vs[b] + (wid * 16 + c * 8) * 64);
    }
  };

  const int n = (q0 + 128) >> 5;    // 32-key iterations: 4..32
  stage(0, 0);

  for (int i = 0; i < n; ++i) {
    const int k0 = i << 5;
    __syncthreads();                // drains prefetch(i); frees buf (i-1)&1
    if (i + 1 < n) stage((i + 1) & 1, k0 + 32);

    if (k0 <= qw + 31) {            // wave-uniform causal live check
      const u16* __restrict__ Kb = Ks[i & 1];
      const u16* __restrict__ Vb = Vs[i & 1];

      // QK: two 16-key subtiles; kf reused across both q-subtiles (nt).
#pragma unroll
      for (int f = 0; f < 2; ++f) {
        bf16x8 kf[4];
#pragma unroll
        for (int c = 0; c < 4; ++c)
          kf[c] = *(const bf16x8*)(Kb + (f * 16 + l16) * 128 +
                                   (((c * 4 + quad) ^ l16) * 8));
        floatx4 st[2];
#pragma unroll
        for (int nt = 0; nt < 2; ++nt) {
          st[nt] = z4;
#pragma unroll
          for (int c = 0; c < 4; ++c) st[nt] = MFMA16(kf[c], qf[nt][c], st[nt]);
        }
        const int kb = k0 + f * 16 + quad * 4;
#pragma unroll
        for (int nt = 0; nt < 2; ++nt) {
          const int qrow = qw + nt * 16 + l16;
          float p[4];
#pragma unroll
          for (int r = 0; r < 4; ++r) {
            const float e = fminf(__expf(st[nt][r] * RSCALE), 85.f);
            p[r] = (kb + r > qrow) ? 0.f : __expf(e);
          }
          lacc[nt] += (p[0] + p[1]) + (p[2] + p[3]);
          uint2 pk;
          pk.x = (u32)f2b(p[0]) | ((u32)f2b(p[1]) << 16);
          pk.y = (u32)f2b(p[2]) | ((u32)f2b(p[3]) << 16);
          // q = nt*16+l16 -> phys row q>>1, half (q&1)*64B; 8B slot f*4+quad;
          // 16B unit (slot>>1) ^ (prow&3).
          const int prow = nt * 8 + (l16 >> 1);
          const int s8 = f * 4 + quad;
          *(uint2*)((char*)Ps[wid] + prow * 128 + (l16 & 1) * 64 +
                    (((s8 >> 1) ^ (prow & 3)) * 16) + (s8 & 1) * 8) = pk;
        }
      }
      asm volatile("s_waitcnt lgkmcnt(0)" ::: "memory");  // own P visible

      // pa[nt]: B[k=key][n=q] from pair-interleaved Ps.
      bf16x8 pa[2];
#pragma unroll
      for (int nt = 0; nt < 2; ++nt) {
        const int prow = nt * 8 + (l16 >> 1);
        pa[nt] = *(const bf16x8*)((char*)Ps[wid] + prow * 128 +
                                  (l16 & 1) * 64 + ((quad ^ (prow & 3)) * 16));
      }
      // vf: A[m=d][k=key] from pair-interleaved Vs; reused for both nt.
#pragma unroll
      for (int dt = 0; dt < 8; ++dt) {
        const int d = dt * 16 + l16;
        const int vr = d >> 1;
        const bf16x8 vf = *(const bf16x8*)(Vb + vr * 64 + (d & 1) * 32 +
                                           ((quad ^ (vr & 3)) * 8));
        o[0][dt] = MFMA16(vf, pa[0], o[0][dt]);
        o[1][dt] = MFMA16(vf, pa[1], o[1][dt]);
      }
    }
  }

  // l reduce across quads (lanes sharing l16), normalize, store.
  float linv[2];
#pragma unroll
  for (int nt = 0; nt < 2; ++nt) {
    float s = lacc[nt];
    s += __shfl_xor(s, 16);
    s += __shfl_xor(s, 32);
    linv[nt] = 1.0f / s;
  }

  // O^T C-layout: col(l16)=q, row(quad*4+r)=d -> contiguous float4.
  float* outp = out + (size_t)(bh >> 3) * 1024 * 1024 + (bh & 7) * 128;
#pragma unroll
  for (int nt = 0; nt < 2; ++nt) {
    const int qrow = qw + nt * 16 + l16;
#pragma unroll
    for (int dt = 0; dt < 8; ++dt) {
      float4 v;
      v.x = o[nt][dt][0] * linv[nt];
      v.y = o[nt][dt][1] * linv[nt];
      v.z = o[nt][dt][2] * linv[nt];
      v.w = o[nt][dt][3] * linv[nt];
      *(float4*)(outp + (size_t)qrow * 1024 + dt * 16 + quad * 4) = v;
    }
  }
}

// ---------------------------------------------------------------------------
extern "C" void kernel_launch(void* const* d_in, const int* in_sizes, int n_in,
                              void* d_out, int out_size, void* d_ws,
                              size_t ws_size, hipStream_t stream) {
  const float* X = (const float*)d_in[0];
  const float* Wq = (const float*)d_in[1];
  const float* bq = (const float*)d_in[2];
  const float* Wk = (const float*)d_in[3];
  const float* bk = (const float*)d_in[4];
  const float* Wv = (const float*)d_in[5];
  const float* bv = (const float*)d_in[6];
  float* out = (float*)d_out;

  char* ws = (char*)d_ws;
  u16* Xb  = (u16*)(ws);                         // 16 MB  bf16 X
  u16* Wtb = (u16*)(ws + (16u << 20));           //  6 MB  bf16 W^T x3
  u16* Qh  = (u16*)(ws + (22u << 20));           // 16 MB  [B,H,S,DH]
  u16* Kh  = (u16*)(ws + (38u << 20));           // 16 MB  [B,H,S,DH]
  u16* Vt  = (u16*)(ws + (54u << 20));           // 16 MB  [B,H,DH,S]

  cast_kernel<<<8192, 256, 0, stream>>>((const float4*)X, Xb);
  dim3 gt(32, 32, 3), bt(32, 8);
  transpose_kernel<<<gt, bt, 0, stream>>>(Wq, Wk, Wv, Wtb);
  dim3 gg(64, 8);
  gemm_qkv_kernel<<<gg, 256, 0, stream>>>(Xb, Wtb, bq, Qh, Vt, 0);
  gemm_qkv_kernel<<<gg, 256, 0, stream>>>(Xb, Wtb, bk, Kh, Vt, 1);
  gemm_qkv_kernel<<<gg, 256, 0, stream>>>(Xb, Wtb, bv, Qh, Vt, 2);
  attn_kernel<<<512, 256, 0, stream>>>(Qh, Kh, Vt, out);
}